// Round 4
// baseline (1827.958 us; speedup 1.0000x reference)
//
#include <hip/hip_runtime.h>
#include <hip/hip_bf16.h>
#include <stdint.h>

#define NN 100000
#define NE 1600000
#define HID 256
#define NGRAPH 64
#define POOL_BLOCKS 256

typedef __attribute__((ext_vector_type(8))) short short8;
typedef __attribute__((ext_vector_type(4))) float f32x4;
typedef __attribute__((ext_vector_type(2))) float f32x2;

static __device__ inline float bf2f(unsigned short u){
  union { unsigned int i; float f; } x; x.i = ((unsigned int)u) << 16; return x.f;
}
static __device__ inline unsigned short f2bf(float f){
  union { float f; unsigned int i; } x; x.f = f;
  unsigned int r = x.i + 0x7fffu + ((x.i >> 16) & 1u);
  return (unsigned short)(r >> 16);
}

struct GArgs {
  const void* A;
  const unsigned short* WT;   // [256][Kp] bf16, zero-padded
  const float* bias;
  unsigned short* C;
  int lda, K, Kp, ldc;
};

// ================= branch GEMM: f32 A, LDS-FREE, direct reg fragments =========
// block 128x128 (4 waves 2x2, wave 64x64), BK=32, 2-deep named-reg pipeline.
// Lane (l15,lk) of wave (wm,wn): A-frag i = 8 f32 at row bm+wm*64+i*16+l15,
// k = k0+lk*8; B-frag j = 8 bf16 at col bn+wn*64+j*16+l15. No barriers.
template<bool AL4>
__global__ __launch_bounds__(256, 2) void gemmf_k(GArgs g0, GArgs g1, int M)
{
  GArgs g = (blockIdx.z == 0) ? g0 : g1;
  const int tid = threadIdx.x, lane = tid & 63, wid = tid >> 6;
  const int wm = wid >> 1, wn = wid & 1;
  const int bm = blockIdx.y * 128, bn = blockIdx.x * 128;
  const int l15 = lane & 15, lk = lane >> 4;
  const int K = g.K, Kp = g.Kp, lda = g.lda, NK = Kp >> 5;
  const float* __restrict__ Af = (const float*)g.A;
  const unsigned short* __restrict__ WT = g.WT;
  const int kb = lk * 8;

  unsigned rbF[4];
#pragma unroll
  for (int i = 0; i < 4; ++i) {
    int gr = bm + wm * 64 + i * 16 + l15; if (gr >= M) gr = M - 1;
    rbF[i] = (unsigned)gr * (unsigned)lda;
  }
  unsigned obB[4];
#pragma unroll
  for (int j = 0; j < 4; ++j)
    obB[j] = (unsigned)(bn + wn * 64 + j * 16 + l15) * (unsigned)Kp;

  f32x2 a0[16], a1[16];
  short8 b0[4], b1[4];
  f32x4 acc[4][4];
#pragma unroll
  for (int i = 0; i < 4; i++)
#pragma unroll
    for (int j = 0; j < 4; j++) acc[i][j] = (f32x4){0.f, 0.f, 0.f, 0.f};

#define LOADA(S, k0_) do{ \
  if ((k0_) + 32 <= K) { \
    if (AL4) { \
      _Pragma("unroll") for (int i = 0; i < 4; ++i){ \
        const float* p = Af + rbF[i] + (k0_) + kb; \
        f32x4 v0 = *(const f32x4*)p, v1 = *(const f32x4*)(p + 4); \
        S[i*4+0] = (f32x2){v0.x, v0.y}; S[i*4+1] = (f32x2){v0.z, v0.w}; \
        S[i*4+2] = (f32x2){v1.x, v1.y}; S[i*4+3] = (f32x2){v1.z, v1.w}; } \
    } else { \
      _Pragma("unroll") for (int i = 0; i < 4; ++i){ \
        const float* p = Af + rbF[i] + (k0_) + kb; \
        _Pragma("unroll") for (int q = 0; q < 4; ++q) S[i*4+q] = *(const f32x2*)(p + 2*q); } \
    } \
  } else { \
    _Pragma("unroll") for (int i = 0; i < 4; ++i){ \
      const float* p = Af + rbF[i]; \
      _Pragma("unroll") for (int q = 0; q < 4; ++q){ \
        int k = (k0_) + kb + 2*q; \
        S[i*4+q].x = (k < K) ? p[k] : 0.f; \
        S[i*4+q].y = (k + 1 < K) ? p[k+1] : 0.f; } } \
  } } while(0)

#define LOADB(S, k0_) do{ \
  _Pragma("unroll") for (int j = 0; j < 4; ++j) \
    S[j] = *(const short8*)(WT + obB[j] + (k0_) + kb); } while(0)

#define CVTMFMA(S, B) do{ \
  short8 af[4]; \
  _Pragma("unroll") for (int i = 0; i < 4; ++i){ \
    union { short8 s; unsigned u[4]; } t; \
    _Pragma("unroll") for (int q = 0; q < 4; ++q) \
      asm("v_cvt_pk_bf16_f32 %0, %1, %2" : "=v"(t.u[q]) : "v"(S[i*4+q].x), "v"(S[i*4+q].y)); \
    af[i] = t.s; } \
  _Pragma("unroll") for (int i = 0; i < 4; ++i) \
    _Pragma("unroll") for (int j = 0; j < 4; ++j) \
      acc[i][j] = __builtin_amdgcn_mfma_f32_16x16x32_bf16(af[i], B[j], acc[i][j], 0, 0, 0); \
  } while(0)

  LOADA(a0, 0); LOADB(b0, 0);
  if (NK > 1) { LOADA(a1, 32); LOADB(b1, 32); }

  for (int t = 0; t < NK; t += 2) {
    { CVTMFMA(a0, b0);
      if (t + 2 < NK) { LOADA(a0, (t + 2) << 5); LOADB(b0, (t + 2) << 5); } }
    { CVTMFMA(a1, b1);
      if (t + 3 < NK) { LOADA(a1, (t + 3) << 5); LOADB(b1, (t + 3) << 5); } }
  }

#pragma unroll
  for (int j = 0; j < 4; j++) {
    int col = bn + wn * 64 + j * 16 + l15;
    float bv = g.bias[col];
#pragma unroll
    for (int i = 0; i < 4; i++) {
#pragma unroll
      for (int r = 0; r < 4; r++) {
        int row = bm + wm * 64 + i * 16 + lk * 4 + r;
        float v = fmaxf(acc[i][j][r] + bv, 0.f);
        unsigned u = f2bf(v);
        unsigned pu = (unsigned)__shfl_xor((int)u, 1);
        if (!(lane & 1) && row < M)
          *(unsigned*)(g.C + (size_t)row * g.ldc + col) = u | (pu << 16);
      }
    }
  }
#undef LOADA
#undef LOADB
#undef CVTMFMA
}

// ================= conv GEMM: bf16 A, LDS-FREE, direct reg fragments ==========
__global__ __launch_bounds__(256, 3) void gemmb_k(GArgs g, int M)
{
  const int tid = threadIdx.x, lane = tid & 63, wid = tid >> 6;
  const int wm = wid >> 1, wn = wid & 1;
  const int bm = blockIdx.y * 128, bn = blockIdx.x * 128;
  const int l15 = lane & 15, lk = lane >> 4;
  const int Kp = g.Kp, lda = g.lda, NK = Kp >> 5;
  const unsigned short* __restrict__ Ab = (const unsigned short*)g.A;
  const unsigned short* __restrict__ WT = g.WT;
  const int kb = lk * 8;

  unsigned rbA[4];
#pragma unroll
  for (int i = 0; i < 4; ++i) {
    int gr = bm + wm * 64 + i * 16 + l15; if (gr >= M) gr = M - 1;
    rbA[i] = (unsigned)gr * (unsigned)lda;
  }
  unsigned obB[4];
#pragma unroll
  for (int j = 0; j < 4; ++j)
    obB[j] = (unsigned)(bn + wn * 64 + j * 16 + l15) * (unsigned)Kp;

  short8 a0[4], a1[4], b0[4], b1[4];
  f32x4 acc[4][4];
#pragma unroll
  for (int i = 0; i < 4; i++)
#pragma unroll
    for (int j = 0; j < 4; j++) acc[i][j] = (f32x4){0.f, 0.f, 0.f, 0.f};

#define LOADAB(SA, SB, k0_) do{ \
  _Pragma("unroll") for (int i = 0; i < 4; ++i) \
    SA[i] = *(const short8*)(Ab + rbA[i] + (k0_) + kb); \
  _Pragma("unroll") for (int j = 0; j < 4; ++j) \
    SB[j] = *(const short8*)(WT + obB[j] + (k0_) + kb); } while(0)

#define DOMFMA(SA, SB) do{ \
  _Pragma("unroll") for (int i = 0; i < 4; ++i) \
    _Pragma("unroll") for (int j = 0; j < 4; ++j) \
      acc[i][j] = __builtin_amdgcn_mfma_f32_16x16x32_bf16(SA[i], SB[j], acc[i][j], 0, 0, 0); \
  } while(0)

  LOADAB(a0, b0, 0);
  if (NK > 1) LOADAB(a1, b1, 32);

  for (int t = 0; t < NK; t += 2) {
    { DOMFMA(a0, b0); if (t + 2 < NK) LOADAB(a0, b0, (t + 2) << 5); }
    { DOMFMA(a1, b1); if (t + 3 < NK) LOADAB(a1, b1, (t + 3) << 5); }
  }

#pragma unroll
  for (int j = 0; j < 4; j++) {
    int col = bn + wn * 64 + j * 16 + l15;
#pragma unroll
    for (int i = 0; i < 4; i++) {
#pragma unroll
      for (int r = 0; r < 4; r++) {
        int row = bm + wm * 64 + i * 16 + lk * 4 + r;
        unsigned u = f2bf(acc[i][j][r]);
        unsigned pu = (unsigned)__shfl_xor((int)u, 1);
        if (!(lane & 1) && row < M)
          *(unsigned*)(g.C + (size_t)row * g.ldc + col) = u | (pu << 16);
      }
    }
  }
#undef LOADAB
#undef DOMFMA
}

// ---------------- weight transpose + pad + bf16 convert ----------------
__global__ void wconv_k(const float* __restrict__ W, unsigned short* __restrict__ WT,
                        int K, int Kp)
{
  int idx = blockIdx.x * 256 + threadIdx.x;
  if (idx >= 256 * Kp) return;
  int n = idx / Kp, k = idx - n * Kp;
  float v = (k < K) ? W[(size_t)k * 256 + n] : 0.f;
  WT[(size_t)n * Kp + k] = f2bf(v);
}

// ---------------- CSR build ----------------
__global__ void zero_int_k(int* p, int n){
  int i = blockIdx.x * 256 + threadIdx.x; if (i < n) p[i] = 0;
}
__global__ void count_k(const int* __restrict__ dst, int* __restrict__ cnt, int n){
  int e = blockIdx.x * 256 + threadIdx.x; if (e < n) atomicAdd(&cnt[dst[e]], 1);
}
__global__ void deg_k(const int* __restrict__ cnt, float* __restrict__ dinv,
                      float* __restrict__ selfc, int n){
  int i = blockIdx.x * 256 + threadIdx.x;
  if (i < n) { float d = 1.0f + (float)cnt[i]; dinv[i] = rsqrtf(d); selfc[i] = 1.0f / d; }
}
__global__ void scan1_k(const int* __restrict__ cnt, int* __restrict__ bsum, int n){
  __shared__ int s[256];
  int b = blockIdx.x, t = threadIdx.x;
  int base = b * 1024 + t * 4, v = 0;
#pragma unroll
  for (int j = 0; j < 4; j++) { int i = base + j; if (i < n) v += cnt[i]; }
  s[t] = v; __syncthreads();
  for (int o = 128; o > 0; o >>= 1) { if (t < o) s[t] += s[t + o]; __syncthreads(); }
  if (t == 0) bsum[b] = s[0];
}
__global__ void scan2_k(int* bsum, int nb){
  __shared__ int s[256];
  int t = threadIdx.x;
  int v = (t < nb) ? bsum[t] : 0;
  s[t] = v; __syncthreads();
  for (int o = 1; o < 256; o <<= 1) {
    int x = (t >= o) ? s[t - o] : 0; __syncthreads();
    s[t] += x; __syncthreads();
  }
  if (t < nb) bsum[t] = s[t] - v;
}
__global__ void scan3_k(const int* __restrict__ cnt, const int* __restrict__ bsum,
                        int* __restrict__ rowstart, int* __restrict__ cursor, int n){
  __shared__ int s[256];
  int b = blockIdx.x, t = threadIdx.x;
  int base = b * 1024 + t * 4;
  int c0 = 0, c1 = 0, c2 = 0, c3 = 0;
  if (base + 0 < n) c0 = cnt[base + 0];
  if (base + 1 < n) c1 = cnt[base + 1];
  if (base + 2 < n) c2 = cnt[base + 2];
  if (base + 3 < n) c3 = cnt[base + 3];
  int ts = c0 + c1 + c2 + c3;
  s[t] = ts; __syncthreads();
  for (int o = 1; o < 256; o <<= 1) {
    int x = (t >= o) ? s[t - o] : 0; __syncthreads();
    s[t] += x; __syncthreads();
  }
  int run = bsum[b] + s[t] - ts;
  int cc[4] = {c0, c1, c2, c3};
#pragma unroll
  for (int j = 0; j < 4; j++) {
    int i = base + j;
    if (i < n) {
      rowstart[i] = run; cursor[i] = run; run += cc[j];
      if (i == n - 1) rowstart[n] = run;
    }
  }
}
__global__ void scatter_k(const int* __restrict__ src, const int* __restrict__ dst,
                          const float* __restrict__ dinv, int* __restrict__ cursor,
                          int* __restrict__ csr_src, float* __restrict__ csr_coef, int n){
  int e = blockIdx.x * 256 + threadIdx.x; if (e >= n) return;
  int d = dst[e], s = src[e];
  int p = atomicAdd(&cursor[d], 1);
  csr_src[p] = s;
  csr_coef[p] = dinv[s] * dinv[d];
}

// ---------------- aggregation ----------------
__global__ __launch_bounds__(256) void agg_k(
    const unsigned short* __restrict__ h,
    const int* __restrict__ rowstart, const int* __restrict__ csr_src,
    const float* __restrict__ csr_coef, const float* __restrict__ selfc,
    const float* __restrict__ bias, unsigned short* __restrict__ out)
{
  int dst = blockIdx.x * 4 + (threadIdx.x >> 6);
  if (dst >= NN) return;
  int lane = threadIdx.x & 63;
  int colb = lane * 4;
  const unsigned short* hb = h + colb;
  ushort4 hv = *(const ushort4*)(hb + (size_t)dst * 256);
  float sc = selfc[dst];
  float a0 = sc * bf2f(hv.x), a1 = sc * bf2f(hv.y), a2 = sc * bf2f(hv.z), a3 = sc * bf2f(hv.w);
  int e0 = rowstart[dst], e1 = rowstart[dst + 1];
  int e = e0;
  for (; e + 8 <= e1; e += 8) {
    int ss[8]; float cc[8]; ushort4 vv[8];
#pragma unroll
    for (int q = 0; q < 8; ++q) { ss[q] = csr_src[e + q]; cc[q] = csr_coef[e + q]; }
#pragma unroll
    for (int q = 0; q < 8; ++q) vv[q] = *(const ushort4*)(hb + (size_t)ss[q] * 256);
#pragma unroll
    for (int q = 0; q < 8; ++q) {
      a0 += cc[q] * bf2f(vv[q].x); a1 += cc[q] * bf2f(vv[q].y);
      a2 += cc[q] * bf2f(vv[q].z); a3 += cc[q] * bf2f(vv[q].w);
    }
  }
  for (; e + 2 <= e1; e += 2) {
    int s0 = csr_src[e], s1 = csr_src[e + 1];
    float c0 = csr_coef[e], c1 = csr_coef[e + 1];
    ushort4 v0 = *(const ushort4*)(hb + (size_t)s0 * 256);
    ushort4 v1 = *(const ushort4*)(hb + (size_t)s1 * 256);
    a0 += c0 * bf2f(v0.x) + c1 * bf2f(v1.x); a1 += c0 * bf2f(v0.y) + c1 * bf2f(v1.y);
    a2 += c0 * bf2f(v0.z) + c1 * bf2f(v1.z); a3 += c0 * bf2f(v0.w) + c1 * bf2f(v1.w);
  }
  if (e < e1) {
    int s0 = csr_src[e]; float c0 = csr_coef[e];
    ushort4 v0 = *(const ushort4*)(hb + (size_t)s0 * 256);
    a0 += c0 * bf2f(v0.x); a1 += c0 * bf2f(v0.y); a2 += c0 * bf2f(v0.z); a3 += c0 * bf2f(v0.w);
  }
  float4 bv = *(const float4*)(bias + colb);
  a0 = fmaxf(a0 + bv.x, 0.f); a1 = fmaxf(a1 + bv.y, 0.f);
  a2 = fmaxf(a2 + bv.z, 0.f); a3 = fmaxf(a3 + bv.w, 0.f);
  ushort4 o; o.x = f2bf(a0); o.y = f2bf(a1); o.z = f2bf(a2); o.w = f2bf(a3);
  *(ushort4*)(out + (size_t)dst * 256 + colb) = o;
}

// ---------------- pooling partials ----------------
__global__ __launch_bounds__(256) void pool_k(
    const unsigned short* __restrict__ x, const int* __restrict__ batch,
    float* __restrict__ pp, float* __restrict__ cp)
{
  __shared__ float acc[NGRAPH][HID];
  __shared__ float cl[NGRAPH];
  int t = threadIdx.x, b = blockIdx.x;
  for (int i = t; i < NGRAPH * HID; i += 256) ((float*)acc)[i] = 0.f;
  if (t < NGRAPH) cl[t] = 0.f;
  __syncthreads();
  int per = (NN + POOL_BLOCKS - 1) / POOL_BLOCKS;
  int i0 = b * per, i1 = min(NN, i0 + per);
  for (int i = i0; i < i1; ++i) {
    int g = batch[i];
    acc[g][t] += bf2f(x[(size_t)i * 256 + t]);
    if (t == 0) cl[g] += 1.f;
  }
  __syncthreads();
  for (int g = 0; g < NGRAPH; ++g) pp[(size_t)b * (NGRAPH * HID) + g * HID + t] = acc[g][t];
  if (t < NGRAPH) cp[b * NGRAPH + t] = cl[t];
}

// ---------------- head ----------------
__global__ __launch_bounds__(256) void head_k(
    const float* __restrict__ pp, const float* __restrict__ cp,
    const float* __restrict__ Wl1, const float* __restrict__ bl1,
    const float* __restrict__ Wl2, const float* __restrict__ bl2,
    float* __restrict__ out)
{
  __shared__ float pooled[HID];
  __shared__ float red[2][4];
  int g = blockIdx.x, t = threadIdx.x;
  float s = 0.f;
  for (int b = 0; b < POOL_BLOCKS; ++b) s += pp[(size_t)b * (NGRAPH * HID) + g * HID + t];
  float cnt = 0.f;
  for (int b = 0; b < POOL_BLOCKS; ++b) cnt += cp[b * NGRAPH + g];
  pooled[t] = s / fmaxf(cnt, 1.f);
  __syncthreads();
  float hv = bl1[t];
  for (int k = 0; k < HID; ++k) hv += pooled[k] * Wl1[k * HID + t];
  hv = fmaxf(hv, 0.f);
  float p0 = hv * Wl2[t * 2 + 0];
  float p1 = hv * Wl2[t * 2 + 1];
  for (int o = 32; o > 0; o >>= 1) { p0 += __shfl_down(p0, o); p1 += __shfl_down(p1, o); }
  int w = t >> 6;
  if ((t & 63) == 0) { red[0][w] = p0; red[1][w] = p1; }
  __syncthreads();
  if (t == 0) {
    float l0 = bl2[0], l1 = bl2[1];
#pragma unroll
    for (int i = 0; i < 4; i++) { l0 += red[0][i]; l1 += red[1][i]; }
    float m = fmaxf(l0, l1);
    float lse = m + logf(expf(l0 - m) + expf(l1 - m));
    out[g * 2 + 0] = l0 - lse;
    out[g * 2 + 1] = l1 - lse;
  }
}

// ---------------- launch ----------------
extern "C" void kernel_launch(void* const* d_in, const int* in_sizes, int n_in,
                              void* d_out, int out_size, void* d_ws, size_t ws_size,
                              hipStream_t stream)
{
  const float* content = (const float*)d_in[0];
  const float* bert    = (const float*)d_in[1];
  const float* profile = (const float*)d_in[2];
  const float* spacy   = (const float*)d_in[3];
  const int*   eidx    = (const int*)d_in[4];
  const int*   batch   = (const int*)d_in[5];
  const float* Wc = (const float*)d_in[6];  const float* bc = (const float*)d_in[7];
  const float* Wb = (const float*)d_in[8];  const float* bb = (const float*)d_in[9];
  const float* Wp = (const float*)d_in[10]; const float* bp = (const float*)d_in[11];
  const float* Ws = (const float*)d_in[12]; const float* bs = (const float*)d_in[13];
  const float* Wg1 = (const float*)d_in[14]; const float* bg1 = (const float*)d_in[15];
  const float* Wg2 = (const float*)d_in[16]; const float* bg2 = (const float*)d_in[17];
  const float* Wl1 = (const float*)d_in[18]; const float* bl1 = (const float*)d_in[19];
  const float* Wl2 = (const float*)d_in[20]; const float* bl2 = (const float*)d_in[21];
  float* out = (float*)d_out;
  const int* srcp = eidx;
  const int* dstp = eidx + NE;

  const int KPC = 320, KPB = 768, KPP = 64, KPS = 320, KPG1 = 1024, KPG2 = 256;

  char* ws = (char*)d_ws;
  size_t off = 0;
  auto alloc = [&](size_t bytes) { size_t o = off; off += (bytes + 255) & ~(size_t)255; return o; };

  unsigned short* WTc  = (unsigned short*)(ws + alloc((size_t)256 * KPC * 2));
  unsigned short* WTb  = (unsigned short*)(ws + alloc((size_t)256 * KPB * 2));
  unsigned short* WTp  = (unsigned short*)(ws + alloc((size_t)256 * KPP * 2));
  unsigned short* WTs  = (unsigned short*)(ws + alloc((size_t)256 * KPS * 2));
  unsigned short* WTg1 = (unsigned short*)(ws + alloc((size_t)256 * KPG1 * 2));
  unsigned short* WTg2 = (unsigned short*)(ws + alloc((size_t)256 * KPG2 * 2));
  float* dinv    = (float*)(ws + alloc((size_t)NN * 4));
  float* selfc   = (float*)(ws + alloc((size_t)NN * 4));
  int* rowcnt    = (int*)(ws + alloc((size_t)NN * 4));
  int* rowstart  = (int*)(ws + alloc((size_t)(NN + 1) * 4));
  int* cursor    = (int*)(ws + alloc((size_t)NN * 4));
  int* csr_src   = (int*)(ws + alloc((size_t)NE * 4));
  float* csr_coef= (float*)(ws + alloc((size_t)NE * 4));
  int* bsum      = (int*)(ws + alloc(1024));
  float* pp      = (float*)(ws + alloc((size_t)POOL_BLOCKS * NGRAPH * HID * 4));
  float* cp      = (float*)(ws + alloc((size_t)POOL_BLOCKS * NGRAPH * 4));
  unsigned short* X1 = (unsigned short*)(ws + alloc((size_t)NN * 1024 * 2));
  unsigned short* H  = (unsigned short*)(ws + alloc((size_t)NN * 256 * 2));
  unsigned short* X2 = (unsigned short*)(ws + alloc((size_t)NN * 256 * 2));
  unsigned short* X3 = (unsigned short*)(ws + alloc((size_t)NN * 256 * 2));
  (void)ws_size; (void)in_sizes; (void)n_in; (void)out_size;

  hipStream_t s = stream;
  const int NB = (NN + 1023) / 1024;
  const int MB = (NN + 127) / 128;    // 782

  wconv_k<<<(256 * KPC + 255) / 256, 256, 0, s>>>(Wc, WTc, 310, KPC);
  wconv_k<<<(256 * KPB + 255) / 256, 256, 0, s>>>(Wb, WTb, 768, KPB);
  wconv_k<<<(256 * KPP + 255) / 256, 256, 0, s>>>(Wp, WTp, 10, KPP);
  wconv_k<<<(256 * KPS + 255) / 256, 256, 0, s>>>(Ws, WTs, 300, KPS);
  wconv_k<<<(256 * KPG1 + 255) / 256, 256, 0, s>>>(Wg1, WTg1, 1024, KPG1);
  wconv_k<<<(256 * KPG2 + 255) / 256, 256, 0, s>>>(Wg2, WTg2, 256, KPG2);

  zero_int_k<<<(NN + 255) / 256, 256, 0, s>>>(rowcnt, NN);
  count_k<<<(NE + 255) / 256, 256, 0, s>>>(dstp, rowcnt, NE);
  deg_k<<<(NN + 255) / 256, 256, 0, s>>>(rowcnt, dinv, selfc, NN);
  scan1_k<<<NB, 256, 0, s>>>(rowcnt, bsum, NN);
  scan2_k<<<1, 256, 0, s>>>(bsum, NB);
  scan3_k<<<NB, 256, 0, s>>>(rowcnt, bsum, rowstart, cursor, NN);
  scatter_k<<<(NE + 255) / 256, 256, 0, s>>>(srcp, dstp, dinv, cursor, csr_src, csr_coef, NE);

  // branch linears + relu -> X1 [N,1024] bf16 (LDS-free GEMMs)
  {
    GArgs gb = { bert,    WTb, bb, X1 + 256, 768, 768, KPB, 1024 };
    GArgs gs = { spacy,   WTs, bs, X1 + 768, 300, 300, KPS, 1024 };
    GArgs gc = { content, WTc, bc, X1 + 0,   310, 310, KPC, 1024 };
    GArgs gp = { profile, WTp, bp, X1 + 512, 10,  10,  KPP, 1024 };
    gemmf_k<true ><<<dim3(2, MB, 2), 256, 0, s>>>(gb, gs, NN);   // lda % 4 == 0
    gemmf_k<false><<<dim3(2, MB, 2), 256, 0, s>>>(gc, gp, NN);   // lda % 4 != 0
  }

  // conv1: H = X1 @ Wg1 ; agg+bias+relu -> X2
  {
    GArgs g1 = { X1, WTg1, nullptr, H, 1024, 1024, KPG1, 256 };
    gemmb_k<<<dim3(2, MB), 256, 0, s>>>(g1, NN);
  }
  agg_k<<<(NN + 3) / 4, 256, 0, s>>>(H, rowstart, csr_src, csr_coef, selfc, bg1, X2);

  // conv2: H = X2 @ Wg2 ; agg+bias+relu -> X3
  {
    GArgs g2 = { X2, WTg2, nullptr, H, 256, 256, KPG2, 256 };
    gemmb_k<<<dim3(2, MB), 256, 0, s>>>(g2, NN);
  }
  agg_k<<<(NN + 3) / 4, 256, 0, s>>>(H, rowstart, csr_src, csr_coef, selfc, bg2, X3);

  pool_k<<<POOL_BLOCKS, 256, 0, s>>>(X3, batch, pp, cp);
  head_k<<<NGRAPH, 256, 0, s>>>(pp, cp, Wl1, bl1, Wl2, bl2, out);
}